// Round 3
// baseline (1283.950 us; speedup 1.0000x reference)
//
#include <hip/hip_runtime.h>
#include <hip/hip_bf16.h>
#include <stdint.h>

typedef __attribute__((ext_vector_type(8))) short short8;
typedef __attribute__((ext_vector_type(4))) float f32x4;

#define ALPHA 1.0f
#define RMS_EPS 1e-6f
#define GAP_THRESH 0.002f

// ---------- helpers ----------

__device__ __forceinline__ unsigned short f2bf(float f) {
  uint32_t u = __builtin_bit_cast(uint32_t, f);
  u = u + 0x7fffu + ((u >> 16) & 1u);   // round-to-nearest-even
  return (unsigned short)(u >> 16);
}

__device__ __forceinline__ float bf2f(unsigned short h) {
  uint32_t u = ((uint32_t)h) << 16;
  return __builtin_bit_cast(float, u);
}

__device__ __forceinline__ void gload_lds16(const void* g, void* l) {
  __builtin_amdgcn_global_load_lds(
      (const __attribute__((address_space(1))) void*)g,
      (__attribute__((address_space(3))) void*)l, 16, 0, 0);
}

__device__ __forceinline__ float brsum(float v, float* sbuf) {
  #pragma unroll
  for (int off = 32; off; off >>= 1) v += __shfl_xor(v, off, 64);
  __syncthreads();
  if ((threadIdx.x & 63) == 0) sbuf[threadIdx.x >> 6] = v;
  __syncthreads();
  return sbuf[0] + sbuf[1] + sbuf[2] + sbuf[3];
}

__device__ __forceinline__ double brsumd(double v, double* sbuf) {
  #pragma unroll
  for (int off = 32; off; off >>= 1) v += __shfl_xor(v, off, 64);
  __syncthreads();
  if ((threadIdx.x & 63) == 0) sbuf[threadIdx.x >> 6] = v;
  __syncthreads();
  return sbuf[0] + sbuf[1] + sbuf[2] + sbuf[3];
}

__device__ __forceinline__ void top2_merge(float& v1, int& i1, float& v2, int& i2,
                                           float w1, int j1, float w2, int j2) {
  if (w1 > v1 || (w1 == v1 && j1 < i1)) {
    float nv2; int ni2;
    if (v1 > w2 || (v1 == w2 && i1 < j2)) { nv2 = v1; ni2 = i1; }
    else { nv2 = w2; ni2 = j2; }
    v2 = nv2; i2 = ni2; v1 = w1; i1 = j1;
  } else {
    if (w1 > v2 || (w1 == v2 && j1 < i2)) { v2 = w1; i2 = j1; }
  }
}

// ---------- prep: raw x -> bf16 hi/lo split + rmsnorm scale ----------

__global__ __launch_bounds__(256) void xprep_kernel(
    const float* __restrict__ x,
    unsigned short* __restrict__ x_hi, unsigned short* __restrict__ x_lo,
    float* __restrict__ scales) {
  __shared__ float sred[4];
  const int row = blockIdx.x, tid = threadIdx.x;
  const float4* xr = (const float4*)(x + (size_t)row * 2048);
  float4 a = xr[tid];
  float4 b = xr[tid + 256];
  float ss = a.x*a.x + a.y*a.y + a.z*a.z + a.w*a.w
           + b.x*b.x + b.y*b.y + b.z*b.z + b.w*b.w;
  ss = brsum(ss, sred);
  if (tid == 0) {
    const float t = ss * (1.0f / 2048.0f) + RMS_EPS;
    scales[row] = 1.0f / sqrtf(t);   // accurate rsqrt via sqrt+div
  }
  float v[8] = {a.x, a.y, a.z, a.w, b.x, b.y, b.z, b.w};
  unsigned short h[8], l[8];
  #pragma unroll
  for (int i = 0; i < 8; ++i) {
    h[i] = f2bf(v[i]);
    l[i] = f2bf(v[i] - bf2f(h[i]));
  }
  ushort4* ho = (ushort4*)(x_hi + (size_t)row * 2048);
  ushort4* lo = (ushort4*)(x_lo + (size_t)row * 2048);
  ho[tid]       = make_ushort4(h[0], h[1], h[2], h[3]);
  ho[tid + 256] = make_ushort4(h[4], h[5], h[6], h[7]);
  lo[tid]       = make_ushort4(l[0], l[1], l[2], l[3]);
  lo[tid + 256] = make_ushort4(l[4], l[5], l[6], l[7]);
}

// ---------- prep: transpose + cast fp32[R][C] -> bf16[C][R] ----------

__global__ __launch_bounds__(256) void transpose_cast_kernel(
    const float* __restrict__ in, unsigned short* __restrict__ out, int R, int C) {
  __shared__ unsigned short tile[32][33];
  const int tx = threadIdx.x, ty = threadIdx.y;
  const int c0 = blockIdx.x * 32, r0 = blockIdx.y * 32;
  #pragma unroll
  for (int i = 0; i < 4; ++i)
    tile[ty + i*8][tx] = f2bf(in[(size_t)(r0 + ty + i*8) * C + c0 + tx]);
  __syncthreads();
  #pragma unroll
  for (int i = 0; i < 4; ++i)
    out[(size_t)(c0 + ty + i*8) * R + r0 + tx] = tile[tx][ty + i*8];
}

// hi/lo variant for LoRA_A
__global__ __launch_bounds__(256) void transpose_cast_hilo_kernel(
    const float* __restrict__ in, unsigned short* __restrict__ out_hi,
    unsigned short* __restrict__ out_lo, int R, int C) {
  __shared__ unsigned short th[32][33];
  __shared__ unsigned short tl[32][33];
  const int tx = threadIdx.x, ty = threadIdx.y;
  const int c0 = blockIdx.x * 32, r0 = blockIdx.y * 32;
  #pragma unroll
  for (int i = 0; i < 4; ++i) {
    float v = in[(size_t)(r0 + ty + i*8) * C + c0 + tx];
    unsigned short h = f2bf(v);
    th[ty + i*8][tx] = h;
    tl[ty + i*8][tx] = f2bf(v - bf2f(h));
  }
  __syncthreads();
  #pragma unroll
  for (int i = 0; i < 4; ++i) {
    out_hi[(size_t)(c0 + ty + i*8) * R + r0 + tx] = th[tx][ty + i*8];
    out_lo[(size_t)(c0 + ty + i*8) * R + r0 + tx] = tl[tx][ty + i*8];
  }
}

// ---------- GEMM: C[M][N] = A[M][K] * B^T (B stored [N][K]), bf16 MFMA ----------
// EPI 0: C(bf16) = gelu(acc + bias)   (H)
// EPI 1: C(f32)  = acc                (act first pass)
// EPI 2: C(f32) += acc + bias         (final out accumulate)
// EPI 3: C(f32) += acc                (act accumulate passes)

template <int EPI>
__global__ __launch_bounds__(256, 2) void gemm_bt_kernel(
    const unsigned short* __restrict__ A, const unsigned short* __restrict__ B,
    const float* __restrict__ bias, void* __restrict__ Cptr,
    int M, int N, int K) {
  __shared__ __align__(16) unsigned short ldsA[128 * 64];
  __shared__ __align__(16) unsigned short ldsB[128 * 64];
  const int tid = threadIdx.x;
  const int wave = tid >> 6, lane = tid & 63;
  const int lo = lane & 15, hi = lane >> 4;
  const int wm = wave >> 1, wn = wave & 1;
  const int m0 = blockIdx.y * 128, n0 = blockIdx.x * 128;

  f32x4 acc[4][4];
  #pragma unroll
  for (int i = 0; i < 4; ++i)
    #pragma unroll
    for (int j = 0; j < 4; ++j) acc[i][j] = (f32x4){0.f, 0.f, 0.f, 0.f};

  const int r_ = tid >> 3, cc_ = tid & 7;
  const int nk = K >> 6;
  for (int kt = 0; kt < nk; ++kt) {
    const int kb = kt << 6;
    #pragma unroll
    for (int i = 0; i < 4; ++i) {
      const int chunk = i * 256 + tid;
      gload_lds16(A + (size_t)(m0 + r_ + i * 32) * K + kb + cc_ * 8, &ldsA[chunk * 8]);
    }
    #pragma unroll
    for (int i = 0; i < 4; ++i) {
      const int chunk = i * 256 + tid;
      gload_lds16(B + (size_t)(n0 + r_ + i * 32) * K + kb + cc_ * 8, &ldsB[chunk * 8]);
    }
    __syncthreads();
    #pragma unroll
    for (int ks = 0; ks < 2; ++ks) {
      short8 af[4], bfr[4];
      #pragma unroll
      for (int mi = 0; mi < 4; ++mi)
        af[mi] = *(const short8*)&ldsA[(wm*64 + mi*16 + lo) * 64 + ks*32 + hi*8];
      #pragma unroll
      for (int ni = 0; ni < 4; ++ni)
        bfr[ni] = *(const short8*)&ldsB[(wn*64 + ni*16 + lo) * 64 + ks*32 + hi*8];
      #pragma unroll
      for (int mi = 0; mi < 4; ++mi)
        #pragma unroll
        for (int ni = 0; ni < 4; ++ni)
          acc[mi][ni] = __builtin_amdgcn_mfma_f32_16x16x32_bf16(
              af[mi], bfr[ni], acc[mi][ni], 0, 0, 0);
    }
    __syncthreads();
  }

  #pragma unroll
  for (int mi = 0; mi < 4; ++mi) {
    #pragma unroll
    for (int ni = 0; ni < 4; ++ni) {
      const int col = n0 + wn*64 + ni*16 + lo;
      const float bv = (EPI == 0 || EPI == 2) ? bias[col] : 0.0f;
      #pragma unroll
      for (int r = 0; r < 4; ++r) {
        const int row = m0 + wm*64 + mi*16 + hi*4 + r;
        float v = acc[mi][ni][r];
        if constexpr (EPI == 0) {
          v += bv;
          float u = 0.7978845608028654f * (v + 0.044715f * v * v * v);
          float th = 1.0f - 2.0f / (1.0f + __expf(2.0f * u));  // tanh(u)
          float g = 0.5f * v * (1.0f + th);
          ((unsigned short*)Cptr)[(size_t)row * N + col] = f2bf(g);
        } else if constexpr (EPI == 1) {
          ((float*)Cptr)[(size_t)row * N + col] = v;
        } else if constexpr (EPI == 2) {
          float* o = (float*)Cptr + (size_t)row * N + col;
          *o = *o + v + bv;
        } else {
          float* o = (float*)Cptr + (size_t)row * N + col;
          *o = *o + v;
        }
      }
    }
  }
}

// ---------- edit select: top-2 over (act*sc - kb), fp64 recheck on near-ties ----------

__global__ __launch_bounds__(256) void edit_select_kernel(
    const float* __restrict__ act,     // [M][1024] raw dot(x, LoRA_A)
    const float* __restrict__ x,       // [M][2048] fp32
    const float* __restrict__ scales,  // [M]
    const float* __restrict__ LA,      // LoRA_A [2048][1024]
    const float* __restrict__ kb,      // kn_bias [1024]
    float* __restrict__ valb, int* __restrict__ idxb) {
  __shared__ float sv1[4], sv2[4];
  __shared__ int si1[4], si2[4];
  __shared__ double sredd[4];
  const int row = blockIdx.x, tid = threadIdx.x;
  const float* arow = act + (size_t)row * 1024;
  const float sc = scales[row];

  float v1 = -3.4e38f, v2 = -3.4e38f; int i1 = 0, i2 = 0;
  #pragma unroll
  for (int t = 0; t < 4; ++t) {
    const int j = tid + t * 256;
    const float v = arow[j] * sc - kb[j];
    top2_merge(v1, i1, v2, i2, v, j, -3.4e38f, 0x7fffffff);
  }
  #pragma unroll
  for (int off = 32; off; off >>= 1) {
    float w1 = __shfl_xor(v1, off, 64);
    int   j1 = __shfl_xor(i1, off, 64);
    float w2 = __shfl_xor(v2, off, 64);
    int   j2 = __shfl_xor(i2, off, 64);
    top2_merge(v1, i1, v2, i2, w1, j1, w2, j2);
  }
  const int wave = tid >> 6;
  if ((tid & 63) == 0) { sv1[wave] = v1; si1[wave] = i1; sv2[wave] = v2; si2[wave] = i2; }
  __syncthreads();
  v1 = sv1[0]; i1 = si1[0]; v2 = sv2[0]; i2 = si2[0];
  #pragma unroll
  for (int w = 1; w < 4; ++w)
    top2_merge(v1, i1, v2, i2, sv1[w], si1[w], sv2[w], si2[w]);
  __syncthreads();

  float val; int idx;
  if (v1 - v2 < GAP_THRESH) {
    // exact fp64 recheck of the two candidates (incl. exact row scale)
    const float* xrow = x + (size_t)row * 2048;
    double s1 = 0.0, s2 = 0.0, ssd = 0.0;
    for (int d = tid; d < 2048; d += 256) {
      const double xv = (double)xrow[d];
      s1 += xv * (double)LA[(size_t)d * 1024 + i1];
      s2 += xv * (double)LA[(size_t)d * 1024 + i2];
      ssd += xv * xv;
    }
    s1 = brsumd(s1, sredd);
    s2 = brsumd(s2, sredd);
    ssd = brsumd(ssd, sredd);
    const double scd = 1.0 / sqrt(ssd * (1.0 / 2048.0) + (double)RMS_EPS);
    const double d1 = s1 * scd - (double)kb[i1];
    const double d2 = s2 * scd - (double)kb[i2];
    if (d2 > d1 || (d2 == d1 && i2 < i1)) { val = (float)d2; idx = i2; }
    else                                   { val = (float)d1; idx = i1; }
  } else {
    val = v1; idx = i1;
  }
  if (tid == 0) {
    valb[row] = fmaxf(val, 0.0f) * ALPHA;
    idxb[row] = idx;
  }
}

// ---------- edit write: out[row][:] = val[row] * LB[idx[row]][:] ----------

__global__ __launch_bounds__(256) void edit_write_kernel(
    const float* __restrict__ valb, const int* __restrict__ idxb,
    const float* __restrict__ LB, float* __restrict__ out) {
  const int row = blockIdx.x, tid = threadIdx.x;
  const float val = valb[row];
  const int idx = idxb[row];
  const float4* brow = (const float4*)(LB + (size_t)idx * 2048);
  float4* orow = (float4*)(out + (size_t)row * 2048);
  #pragma unroll
  for (int t = 0; t < 2; ++t) {
    float4 b4 = brow[tid + t * 256];
    orow[tid + t * 256] = make_float4(val * b4.x, val * b4.y, val * b4.z, val * b4.w);
  }
}

// ---------- launch ----------

extern "C" void kernel_launch(void* const* d_in, const int* in_sizes, int n_in,
                              void* d_out, int out_size, void* d_ws, size_t ws_size,
                              hipStream_t stream) {
  const float* x  = (const float*)d_in[0];
  const float* W1 = (const float*)d_in[1];
  const float* b1 = (const float*)d_in[2];
  const float* W2 = (const float*)d_in[3];
  const float* b2 = (const float*)d_in[4];
  const float* LA = (const float*)d_in[5];
  const float* LB = (const float*)d_in[6];
  const float* kb = (const float*)d_in[7];

  const int M = 8192, D = 2048, F = 8192, R = 1024;
  const size_t MiB = 1ull << 20;

  // Fixed workspace region: 105 MiB.
  char* ws = (char*)d_ws;
  unsigned short* x_hi  = (unsigned short*)(ws);                 // 32 MiB [M][D]
  unsigned short* W1T   = (unsigned short*)(ws + 32 * MiB);      // 32 MiB [F][D]
  unsigned short* W2T   = (unsigned short*)(ws + 64 * MiB);      // 32 MiB [D][F]
  unsigned short* AT_hi = (unsigned short*)(ws + 96 * MiB);      // 4 MiB  [R][D]
  unsigned short* AT_lo = (unsigned short*)(ws + 100 * MiB);     // 4 MiB  [R][D]
  float*          scales= (float*)(ws + 104 * MiB);              // 32 KiB
  float*          valb  = (float*)(ws + 104 * MiB + 32768);      // 32 KiB
  int*            idxb  = (int*)  (ws + 104 * MiB + 65536);      // 32 KiB
  const size_t off_X = 105 * MiB;
  // Region X: phase 1 holds x_lo (32 MiB); phase 2 holds H (up to 128 MiB, chunked).
  unsigned short* x_lo  = (unsigned short*)(ws + off_X);
  unsigned short* H     = (unsigned short*)(ws + off_X);
  // act [M][R] f32 (32 MiB) lives in the output buffer (dead before out is written).
  float* act = (float*)d_out;

  // H chunking to fit remaining workspace (deterministic in ws_size -> graph-safe).
  size_t HX = (ws_size > off_X) ? (ws_size - off_X) : 0;
  int chunkM = (int)(HX / ((size_t)F * 2));
  chunkM &= ~127;
  if (chunkM < 128) chunkM = 128;
  if (chunkM > M) chunkM = M;

  // prep
  xprep_kernel<<<dim3(M), dim3(256), 0, stream>>>(x, x_hi, x_lo, scales);
  transpose_cast_kernel<<<dim3(F/32, D/32), dim3(32, 8), 0, stream>>>(W1, W1T, D, F);
  transpose_cast_kernel<<<dim3(D/32, F/32), dim3(32, 8), 0, stream>>>(W2, W2T, F, D);
  transpose_cast_hilo_kernel<<<dim3(R/32, D/32), dim3(32, 8), 0, stream>>>(LA, AT_hi, AT_lo, D, R);

  // LoRA edit path: split-precision act = xh*Ah + xh*Al + xl*Ah  (act in d_out)
  gemm_bt_kernel<1><<<dim3(R/128, M/128), dim3(256), 0, stream>>>(x_hi, AT_hi, nullptr, (void*)act, M, R, D);
  gemm_bt_kernel<3><<<dim3(R/128, M/128), dim3(256), 0, stream>>>(x_hi, AT_lo, nullptr, (void*)act, M, R, D);
  gemm_bt_kernel<3><<<dim3(R/128, M/128), dim3(256), 0, stream>>>(x_lo, AT_hi, nullptr, (void*)act, M, R, D);
  edit_select_kernel<<<dim3(M), dim3(256), 0, stream>>>(act, x, scales, LA, kb, valb, idxb);
  edit_write_kernel<<<dim3(M), dim3(256), 0, stream>>>(valb, idxb, LB, (float*)d_out);

  // base path (chunked over M to fit H in workspace), accumulating onto d_out
  for (int mb = 0; mb < M; mb += chunkM) {
    const int cm = (M - mb < chunkM) ? (M - mb) : chunkM;
    gemm_bt_kernel<0><<<dim3(F/128, cm/128), dim3(256), 0, stream>>>(
        x_hi + (size_t)mb * D, W1T, b1, (void*)H, cm, F, D);
    gemm_bt_kernel<2><<<dim3(D/128, cm/128), dim3(256), 0, stream>>>(
        H, W2T, b2, (void*)((float*)d_out + (size_t)mb * D), cm, D, F);
  }
}